// Round 3
// baseline (1588.816 us; speedup 1.0000x reference)
//
#include <hip/hip_runtime.h>

#define DEV __device__ __forceinline__

typedef short bf16x8 __attribute__((ext_vector_type(8)));
typedef float f32x4 __attribute__((ext_vector_type(4)));

static const int NVOX = 262144; // 64^3

DEV float bflo(unsigned int u) { return __uint_as_float(u << 16); }
DEV float bfhi(unsigned int u) { return __uint_as_float(u & 0xffff0000u); }
DEV float bf2f(unsigned short s) { return __uint_as_float(((unsigned int)s) << 16); }
DEV unsigned short f2bf(float f) {
    unsigned int x = __float_as_uint(f);
    x += 0x7fffu + ((x >> 16) & 1u);   // RNE
    return (unsigned short)(x >> 16);
}
// dual-dtype raw-input load: f==1 -> fp32, f==0 -> bf16
DEV float ldin(const void* p, int i, int f) {
    return f ? ((const float*)p)[i] : bf2f(((const unsigned short*)p)[i]);
}

// ---------------------------------------------------------------------------
// Dtype sniffer: bf16 N(0,1) data never has |x| >= 2^18 (u16 masked >= 0x4900).
// fp32 read as u16 has uniform low half-words -> ~43% exceed the mask.
// ---------------------------------------------------------------------------
__global__ void sniff_kernel(const unsigned short* __restrict__ src, int* __restrict__ flag) {
    __shared__ int cnt[256];
    int t = threadIdx.x;
    int c = 0;
    for (int i = t; i < 4096; i += 256) {
        unsigned int u = (unsigned int)src[i] & 0x7fffu;
        c += (u >= 0x4900u) ? 1 : 0;
    }
    cnt[t] = c;
    __syncthreads();
    for (int s = 128; s > 0; s >>= 1) {
        if (t < s) cnt[t] += cnt[t + s];
        __syncthreads();
    }
    if (t == 0) *flag = (cnt[0] > 8) ? 1 : 0;
}

// ---------------------------------------------------------------------------
// Weight prep: Wb1[t][o][cp] (cp padded 130->160, zeros), Wb2[t][o][c],
// plus 4 bias vectors converted to f32.
// ---------------------------------------------------------------------------
__global__ void prep_kernel(const void* __restrict__ w1, const void* __restrict__ w2,
                            const void* __restrict__ bsv, const void* __restrict__ btv,
                            const void* __restrict__ b1v, const void* __restrict__ b2v,
                            const int* __restrict__ flag,
                            unsigned short* __restrict__ Wb1,
                            unsigned short* __restrict__ Wb2,
                            float* __restrict__ fbias) {
    const int f = *flag;
    int idx = blockIdx.x * 256 + threadIdx.x;
    const int N1 = 27 * 64 * 160;   // 276480
    const int N2 = 27 * 64 * 64;    // 110592
    if (idx < N1) {
        int t = idx / (64 * 160);
        int r = idx % (64 * 160);
        int o = r / 160, cp = r % 160;
        unsigned short val = 0;
        if (cp < 130) val = f2bf(ldin(w1, (o * 130 + cp) * 27 + t, f));
        Wb1[idx] = val;
    } else if (idx < N1 + N2) {
        int j = idx - N1;
        int t = j >> 12, r = j & 4095;
        int o = r >> 6, c = r & 63;
        Wb2[j] = f2bf(ldin(w2, (o * 64 + c) * 27 + t, f));
    } else if (idx < N1 + N2 + 256) {
        int j = idx - N1 - N2;
        const void* bp = (j < 64) ? bsv : (j < 128) ? btv : (j < 192) ? b1v : b2v;
        fbias[j] = ldin(bp, j & 63, f);
    }
}

// ---------------------------------------------------------------------------
// Projection (1x1x1 conv 32->64) + L2 normalize over channels.
// Input [32][262144], output [v][64] bf16. blockIdx.y: 0=src->SP, 1=tgt->TP
// ---------------------------------------------------------------------------
__global__ __launch_bounds__(256) void proj_kernel(
        const void* __restrict__ Xsrc, const void* __restrict__ Xtgt,
        const void* __restrict__ Wsrc, const void* __restrict__ Wtgt,
        const float* __restrict__ fbias, const int* __restrict__ flag,
        unsigned short* __restrict__ SP, unsigned short* __restrict__ TP) {
    const int f = *flag;
    const void* Xin = blockIdx.y ? Xtgt : Xsrc;
    const void* W   = blockIdx.y ? Wtgt : Wsrc;
    const float* Bb = fbias + (blockIdx.y ? 64 : 0);
    unsigned short* Outp = blockIdx.y ? TP : SP;

    __shared__ float ws[2048];   // [ci][o]
    const int t = threadIdx.x;
    for (int i = t; i < 2048; i += 256) {
        int ci = i >> 6, o = i & 63;
        ws[i] = ldin(W, o * 32 + ci, f);
    }
    __syncthreads();

    const size_t v = (size_t)blockIdx.x * 256 + t;
    float acc[64];
#pragma unroll
    for (int o = 0; o < 64; ++o) acc[o] = Bb[o];
    if (f) {
        const float* Xf = (const float*)Xin;
        for (int ci = 0; ci < 32; ++ci) {
            float x = Xf[(size_t)ci * NVOX + v];
            const float4* wr = (const float4*)(ws + ci * 64);
#pragma unroll
            for (int o4 = 0; o4 < 16; ++o4) {
                float4 w4 = wr[o4];
                acc[o4 * 4 + 0] = fmaf(w4.x, x, acc[o4 * 4 + 0]);
                acc[o4 * 4 + 1] = fmaf(w4.y, x, acc[o4 * 4 + 1]);
                acc[o4 * 4 + 2] = fmaf(w4.z, x, acc[o4 * 4 + 2]);
                acc[o4 * 4 + 3] = fmaf(w4.w, x, acc[o4 * 4 + 3]);
            }
        }
    } else {
        const unsigned short* Xb = (const unsigned short*)Xin;
        for (int ci = 0; ci < 32; ++ci) {
            float x = bf2f(Xb[(size_t)ci * NVOX + v]);
            const float4* wr = (const float4*)(ws + ci * 64);
#pragma unroll
            for (int o4 = 0; o4 < 16; ++o4) {
                float4 w4 = wr[o4];
                acc[o4 * 4 + 0] = fmaf(w4.x, x, acc[o4 * 4 + 0]);
                acc[o4 * 4 + 1] = fmaf(w4.y, x, acc[o4 * 4 + 1]);
                acc[o4 * 4 + 2] = fmaf(w4.z, x, acc[o4 * 4 + 2]);
                acc[o4 * 4 + 3] = fmaf(w4.w, x, acc[o4 * 4 + 3]);
            }
        }
    }
    float s = 0.f;
#pragma unroll
    for (int o = 0; o < 64; ++o) s = fmaf(acc[o], acc[o], s);
    float scale = 1.f / fmaxf(sqrtf(s), 1e-12f);

    unsigned int pk[32];
#pragma unroll
    for (int o = 0; o < 32; ++o)
        pk[o] = (unsigned int)f2bf(acc[2 * o] * scale) |
                ((unsigned int)f2bf(acc[2 * o + 1] * scale) << 16);
    uint4* outp = (uint4*)(Outp + v * 64);
#pragma unroll
    for (int j = 0; j < 8; ++j)
        outp[j] = make_uint4(pk[4 * j], pk[4 * j + 1], pk[4 * j + 2], pk[4 * j + 3]);
}

// ---------------------------------------------------------------------------
// Correlation (125 offsets, replicate pad) + online softmax/top-2 +
// enc_in assembly [v][160] bf16 + 6 small fp32 output planes.
// Tile (z,y,x)=(2,4,16)=128 voxels, 2 threads/voxel (channel halves).
// ---------------------------------------------------------------------------
__global__ __launch_bounds__(256) void corr_kernel(
        const unsigned short* __restrict__ SP, const unsigned short* __restrict__ TP,
        unsigned short* __restrict__ X1, float* __restrict__ Out) {
    __shared__ unsigned short stage[128 * 168];
    const int t = threadIdx.x;
    const int vi = t >> 1, h = t & 1;
    const int vx = vi & 15, vy = (vi >> 4) & 3, vz = vi >> 6;
    const int X = blockIdx.x * 16 + vx, Y = blockIdx.y * 4 + vy, Z = blockIdx.z * 2 + vz;
    const size_t v = ((size_t)Z * 64 + Y) * 64 + X;

    for (int i = t; i < 128 * 30; i += 256)
        stage[(i / 30) * 168 + 130 + (i % 30)] = 0;

    float spv[32];
    {
        const uint4* p = (const uint4*)(SP + v * 64 + h * 32);
#pragma unroll
        for (int j = 0; j < 4; ++j) {
            uint4 u = p[j];
            spv[j * 8 + 0] = bflo(u.x); spv[j * 8 + 1] = bfhi(u.x);
            spv[j * 8 + 2] = bflo(u.y); spv[j * 8 + 3] = bfhi(u.y);
            spv[j * 8 + 4] = bflo(u.z); spv[j * 8 + 5] = bfhi(u.z);
            spv[j * 8 + 6] = bflo(u.w); spv[j * 8 + 7] = bfhi(u.w);
        }
    }

    float m = -1e30f, s2 = -1e30f, Zs = 0.f, S1 = 0.f, Ox = 0.f, Oy = 0.f, Oz = 0.f;
    int k = 0;
    for (int dz = -2; dz <= 2; ++dz) {
        int zc = min(max(Z + dz, 0), 63);
        for (int dy = -2; dy <= 2; ++dy) {
            int yc = min(max(Y + dy, 0), 63);
            const size_t rowb = ((size_t)zc * 64 + yc) * 64;
            for (int dx = -2; dx <= 2; ++dx, ++k) {
                int xc = min(max(X + dx, 0), 63);
                const uint4* q = (const uint4*)(TP + (rowb + xc) * 64 + h * 32);
                float d = 0.f;
#pragma unroll
                for (int j = 0; j < 4; ++j) {
                    uint4 u = q[j];
                    d = fmaf(bflo(u.x), spv[j * 8 + 0], d); d = fmaf(bfhi(u.x), spv[j * 8 + 1], d);
                    d = fmaf(bflo(u.y), spv[j * 8 + 2], d); d = fmaf(bfhi(u.y), spv[j * 8 + 3], d);
                    d = fmaf(bflo(u.z), spv[j * 8 + 4], d); d = fmaf(bfhi(u.z), spv[j * 8 + 5], d);
                    d = fmaf(bflo(u.w), spv[j * 8 + 6], d); d = fmaf(bfhi(u.w), spv[j * 8 + 7], d);
                }
                d += __shfl_xor(d, 1);
                if (h == 0) stage[vi * 168 + k] = f2bf(d);
                float fx = (float)dx, fy = (float)dy, fz = (float)dz;
                if (d > m) {
                    float sc = __expf(m - d);
                    Zs = fmaf(Zs, sc, 1.f); S1 = fmaf(S1, sc, d);
                    Ox = fmaf(Ox, sc, fx); Oy = fmaf(Oy, sc, fy); Oz = fmaf(Oz, sc, fz);
                    s2 = m; m = d;
                } else {
                    float e = __expf(d - m);
                    Zs += e; S1 = fmaf(e, d, S1);
                    Ox = fmaf(e, fx, Ox); Oy = fmaf(e, fy, Oy); Oz = fmaf(e, fz, Oz);
                    s2 = fmaxf(s2, d);
                }
            }
        }
    }

    if (h == 0) {
        float inv  = 1.f / fmaxf(Zs, 1e-8f);
        float eoz = Oz * inv, eoy = Oy * inv, eox = Ox * inv;
        float conf = fminf(inv, 1.f);
        float marg = fmaxf(conf - __expf(s2 - m) * inv, 0.f);
        float ent  = m + __logf(fmaxf(Zs, 1e-8f)) - S1 * inv;
        stage[vi * 168 + 125] = f2bf(eoz);
        stage[vi * 168 + 126] = f2bf(eoy);
        stage[vi * 168 + 127] = f2bf(eox);
        stage[vi * 168 + 128] = f2bf(conf);
        stage[vi * 168 + 129] = f2bf(ent);
        Out[v]                    = eoz;
        Out[(size_t)NVOX + v]     = eoy;
        Out[(size_t)2 * NVOX + v] = eox;
        Out[(size_t)3 * NVOX + v] = conf;
        Out[(size_t)4 * NVOX + v] = marg;
        Out[(size_t)5 * NVOX + v] = ent;
    }
    __syncthreads();

    const int bx = blockIdx.x * 16, by = blockIdx.y * 4, bz = blockIdx.z * 2;
    for (int idx = t; idx < 128 * 20; idx += 256) {
        int r = idx / 20, cc = idx % 20;
        int rx = r & 15, ry = (r >> 4) & 3, rz = r >> 6;
        size_t gv = ((size_t)(bz + rz) * 64 + (by + ry)) * 64 + (bx + rx);
        *(uint4*)(X1 + gv * 160 + (size_t)cc * 8) = *(const uint4*)(&stage[r * 168 + cc * 8]);
    }
}

// ---------------------------------------------------------------------------
// 3x3x3 conv, implicit GEMM via mfma_f32_16x16x32_bf16, zero padding.
// Block = one (z,y) x-row: 64 voxels x 64 out-ch.
// ---------------------------------------------------------------------------
template <int CPAD, int LSTRIDE, int KC>
__global__ __launch_bounds__(256) void conv3_kernel(
        const unsigned short* __restrict__ Xin, const unsigned short* __restrict__ Wb,
        const float* __restrict__ Bias, unsigned short* __restrict__ Out) {
    __shared__ unsigned short row[66 * LSTRIDE];
    const int y = blockIdx.x, z = blockIdx.y;
    const int t = threadIdx.x;
    const int wv = t >> 6, lane = t & 63;
    const int quad = lane >> 4, l16 = lane & 15;
    f32x4 acc[4] = {{0.f,0.f,0.f,0.f},{0.f,0.f,0.f,0.f},{0.f,0.f,0.f,0.f},{0.f,0.f,0.f,0.f}};
    const int CH16 = CPAD / 8;

    for (int dz = -1; dz <= 1; ++dz) {
        const int zz = z + dz;
        if (zz < 0 || zz > 63) continue;
        for (int dy = -1; dy <= 1; ++dy) {
            const int yy = y + dy;
            if (yy < 0 || yy > 63) continue;
            __syncthreads();
            for (int idx = t; idx < 66 * CH16; idx += 256) {
                int xi = idx / CH16, ci = idx % CH16;
                uint4 val = make_uint4(0u, 0u, 0u, 0u);
                int gx = xi - 1;
                if (gx >= 0 && gx < 64)
                    val = *(const uint4*)(Xin + (((size_t)zz * 64 + yy) * 64 + gx) * CPAD + ci * 8);
                *(uint4*)(&row[xi * LSTRIDE + ci * 8]) = val;
            }
            __syncthreads();
#pragma unroll
            for (int dx = -1; dx <= 1; ++dx) {
                const int tap = (dz + 1) * 9 + (dy + 1) * 3 + (dx + 1);
                const unsigned short* wt = Wb + (size_t)tap * 64 * CPAD;
#pragma unroll
                for (int kc = 0; kc < KC; ++kc) {
                    const int kof = kc * 32 + quad * 8;
                    bf16x8 a = *(const bf16x8*)(&row[(wv * 16 + l16 + dx + 1) * LSTRIDE + kof]);
#pragma unroll
                    for (int nt = 0; nt < 4; ++nt) {
                        bf16x8 b = *(const bf16x8*)(wt + (size_t)(nt * 16 + l16) * CPAD + kof);
                        acc[nt] = __builtin_amdgcn_mfma_f32_16x16x32_bf16(a, b, acc[nt], 0, 0, 0);
                    }
                }
            }
        }
    }

    const size_t vbase = ((size_t)z * 64 + y) * 64 + wv * 16;
#pragma unroll
    for (int nt = 0; nt < 4; ++nt) {
        const int oc = nt * 16 + l16;
        const float bv = Bias[oc];
#pragma unroll
        for (int r = 0; r < 4; ++r) {
            Out[(vbase + quad * 4 + r) * 64 + oc] = f2bf(acc[nt][r] + bv);
        }
    }
}

// ---------------------------------------------------------------------------
// Per-channel sum / sumsq over all voxels (InstanceNorm stats).
// ---------------------------------------------------------------------------
__global__ __launch_bounds__(256) void stats_kernel(
        const unsigned short* __restrict__ H, float* __restrict__ stats) {
    const int t = threadIdx.x;
    const int c = t & 63, g = t >> 6;
    float s = 0.f, q = 0.f;
    for (int v = blockIdx.x * 4 + g; v < NVOX; v += gridDim.x * 4) {
        float x = bf2f(H[(size_t)v * 64 + c]);
        s += x; q = fmaf(x, x, q);
    }
    __shared__ float ls[256], lq[256];
    ls[t] = s; lq[t] = q;
    __syncthreads();
    if (t < 64) {
        s = ls[t] + ls[t + 64] + ls[t + 128] + ls[t + 192];
        q = lq[t] + lq[t + 64] + lq[t + 128] + lq[t + 192];
        atomicAdd(&stats[c], s);
        atomicAdd(&stats[64 + c], q);
    }
}

__global__ void finalize_kernel(const float* __restrict__ stats, float* __restrict__ musr) {
    int c = threadIdx.x;
    if (c < 64) {
        float mu  = stats[c] * (1.0f / 262144.0f);
        float var = stats[64 + c] * (1.0f / 262144.0f) - mu * mu;
        musr[c] = mu;
        musr[64 + c] = rsqrtf(var + 1e-5f);
    }
}

// ---------------------------------------------------------------------------
// Elementwise InstanceNorm + exact GELU, [v][64] -> [v][64] bf16
// ---------------------------------------------------------------------------
__global__ __launch_bounds__(256) void norm_gelu_kernel(
        const unsigned short* __restrict__ H, const float* __restrict__ musr,
        unsigned short* __restrict__ G) {
    const size_t base = ((size_t)blockIdx.x * 256 + threadIdx.x) * 8;
    uint4 u = *(const uint4*)(H + base);
    const int c0 = (int)(base & 63);
    const unsigned int uu[4] = {u.x, u.y, u.z, u.w};
    unsigned int w[4];
#pragma unroll
    for (int p = 0; p < 4; ++p) {
        int c = c0 + p * 2;
        float x0 = (bflo(uu[p]) - musr[c]) * musr[64 + c];
        float x1 = (bfhi(uu[p]) - musr[c + 1]) * musr[64 + c + 1];
        float g0 = 0.5f * x0 * (1.f + erff(x0 * 0.70710678118f));
        float g1 = 0.5f * x1 * (1.f + erff(x1 * 0.70710678118f));
        w[p] = (unsigned int)f2bf(g0) | ((unsigned int)f2bf(g1) << 16);
    }
    *(uint4*)(G + base) = make_uint4(w[0], w[1], w[2], w[3]);
}

// ---------------------------------------------------------------------------
// Final: InstanceNorm + exact GELU on h2, write fp32 channel planes [64][v].
// LDS tile is channel-major fp32 (stride 260 floats -> 16B-aligned float4).
// ---------------------------------------------------------------------------
__global__ __launch_bounds__(256) void out_final_kernel(
        const unsigned short* __restrict__ H2, const float* __restrict__ musr,
        float* __restrict__ OutEnc) {
    __shared__ float tile[64 * 260];
    const int t = threadIdx.x;
    const size_t v0 = (size_t)blockIdx.x * 256;
#pragma unroll
    for (int i = 0; i < 8; ++i) {
        int chunk = t + i * 256;                  // 0..2047
        uint4 u = *(const uint4*)(H2 + v0 * 64 + (size_t)chunk * 8);
        int vox = chunk >> 3;
        int c0 = (chunk & 7) * 8;
        const unsigned int uu[4] = {u.x, u.y, u.z, u.w};
#pragma unroll
        for (int p = 0; p < 4; ++p) {
            int c = c0 + p * 2;
            float x0 = (bflo(uu[p]) - musr[c]) * musr[64 + c];
            float x1 = (bfhi(uu[p]) - musr[c + 1]) * musr[64 + c + 1];
            tile[c * 260 + vox]       = 0.5f * x0 * (1.f + erff(x0 * 0.70710678118f));
            tile[(c + 1) * 260 + vox] = 0.5f * x1 * (1.f + erff(x1 * 0.70710678118f));
        }
    }
    __syncthreads();
    const int c = t >> 2, sub = t & 3;
#pragma unroll
    for (int iter = 0; iter < 16; ++iter) {
        int fq = iter * 4 + sub;                  // float4 index 0..63
        float4 val = *(const float4*)(&tile[c * 260 + fq * 4]);
        *(float4*)(OutEnc + (size_t)c * NVOX + v0 + fq * 4) = val;
    }
}

// ---------------------------------------------------------------------------
extern "C" void kernel_launch(void* const* d_in, const int* in_sizes, int n_in,
                              void* d_out, int out_size, void* d_ws, size_t ws_size,
                              hipStream_t stream) {
    const void* src  = d_in[0];
    const void* tgt  = d_in[1];
    const void* wsrc = d_in[2];
    const void* bsrc = d_in[3];
    const void* wtgt = d_in[4];
    const void* btgt = d_in[5];
    const void* w1   = d_in[6];
    const void* b1   = d_in[7];
    const void* w2   = d_in[8];
    const void* b2   = d_in[9];
    float* out = (float*)d_out;   // fp32 outputs, 70*262144 elements

    char* ws = (char*)d_ws;
    unsigned short* TPb = (unsigned short*)(ws);                  // 33,554,432 B
    unsigned short* SPb = (unsigned short*)(ws + 33554432);       // 33,554,432 B
    unsigned short* X1  = (unsigned short*)(ws + 67108864);       // 83,886,080 B
    unsigned short* Wb1 = (unsigned short*)(ws + 150994944);      //    552,960 B
    unsigned short* Wb2 = (unsigned short*)(ws + 151547904);      //    221,184 B
    int*   flag   = (int*)  (ws + 151769088);
    float* fbias  = (float*)(ws + 151769152);                     // 256 f32
    float* stats1 = (float*)(ws + 151770176);                     // 128 f32
    float* musr1  = (float*)(ws + 151770688);
    float* stats2 = (float*)(ws + 151771200);
    float* musr2  = (float*)(ws + 151771712);
    // Reuse after corr: H1 -> SP slot, G1 -> TP slot, H2 -> X1 slot
    unsigned short* H1 = SPb;
    unsigned short* G1 = TPb;
    unsigned short* H2 = X1;

    (void)hipMemsetAsync(stats1, 0, 2048, stream);
    sniff_kernel<<<1, 256, 0, stream>>>((const unsigned short*)src, flag);
    prep_kernel<<<1513, 256, 0, stream>>>(w1, w2, bsrc, btgt, b1, b2, flag, Wb1, Wb2, fbias);
    proj_kernel<<<dim3(1024, 2), 256, 0, stream>>>(src, tgt, wsrc, wtgt, fbias, flag, SPb, TPb);
    corr_kernel<<<dim3(4, 16, 32), 256, 0, stream>>>(SPb, TPb, X1, out);
    conv3_kernel<160, 168, 5><<<dim3(64, 64), 256, 0, stream>>>(X1, Wb1, fbias + 128, H1);
    stats_kernel<<<256, 256, 0, stream>>>(H1, stats1);
    finalize_kernel<<<1, 64, 0, stream>>>(stats1, musr1);
    norm_gelu_kernel<<<8192, 256, 0, stream>>>(H1, musr1, G1);
    conv3_kernel<64, 72, 2><<<dim3(64, 64), 256, 0, stream>>>(G1, Wb2, fbias + 192, H2);
    stats_kernel<<<256, 256, 0, stream>>>(H2, stats2);
    finalize_kernel<<<1, 64, 0, stream>>>(stats2, musr2);
    out_final_kernel<<<1024, 256, 0, stream>>>(H2, musr2, out + 6 * (size_t)NVOX);
}

// Round 4
// 1030.133 us; speedup vs baseline: 1.5423x; 1.5423x over previous
//
#include <hip/hip_runtime.h>

#define DEV __device__ __forceinline__

typedef short bf16x8 __attribute__((ext_vector_type(8)));
typedef float f32x4 __attribute__((ext_vector_type(4)));

static const int NVOX = 262144; // 64^3

DEV float bflo(unsigned int u) { return __uint_as_float(u << 16); }
DEV float bfhi(unsigned int u) { return __uint_as_float(u & 0xffff0000u); }
DEV float bf2f(unsigned short s) { return __uint_as_float(((unsigned int)s) << 16); }
DEV unsigned short f2bf(float f) {
    unsigned int x = __float_as_uint(f);
    x += 0x7fffu + ((x >> 16) & 1u);   // RNE
    return (unsigned short)(x >> 16);
}
// dual-dtype raw-input load: f==1 -> fp32, f==0 -> bf16
DEV float ldin(const void* p, int i, int f) {
    return f ? ((const float*)p)[i] : bf2f(((const unsigned short*)p)[i]);
}

// ---------------------------------------------------------------------------
// Dtype sniffer (insurance; R3 confirmed fp32 inputs).
// ---------------------------------------------------------------------------
__global__ void sniff_kernel(const unsigned short* __restrict__ src, int* __restrict__ flag) {
    __shared__ int cnt[256];
    int t = threadIdx.x;
    int c = 0;
    for (int i = t; i < 4096; i += 256) {
        unsigned int u = (unsigned int)src[i] & 0x7fffu;
        c += (u >= 0x4900u) ? 1 : 0;
    }
    cnt[t] = c;
    __syncthreads();
    for (int s = 128; s > 0; s >>= 1) {
        if (t < s) cnt[t] += cnt[t + s];
        __syncthreads();
    }
    if (t == 0) *flag = (cnt[0] > 8) ? 1 : 0;
}

// ---------------------------------------------------------------------------
// Weight prep into MFMA B-fragment order:
//   Wf[tap][kc][nt][lane][j]  (j=0..7, lane=0..63), 512 shorts per fragment.
//   Fragment element (lane,j) = W[o = nt*16 + (lane&15)][cp = kc*32 + (lane>>4)*8 + j]
// conv1: KC=5, cp<130 real else 0, src w1[(o*130+cp)*27 + tap]
// conv2: KC=2, src w2[(o*64+c)*27 + tap]
// Plus 4 bias vectors converted to f32.
// ---------------------------------------------------------------------------
__global__ void prep_kernel(const void* __restrict__ w1, const void* __restrict__ w2,
                            const void* __restrict__ bsv, const void* __restrict__ btv,
                            const void* __restrict__ b1v, const void* __restrict__ b2v,
                            const int* __restrict__ flag,
                            unsigned short* __restrict__ Wf1,
                            unsigned short* __restrict__ Wf2,
                            float* __restrict__ fbias) {
    const int f = *flag;
    int idx = blockIdx.x * 256 + threadIdx.x;
    const int N1 = 27 * 5 * 4 * 512;   // 276480
    const int N2 = 27 * 2 * 4 * 512;   // 110592
    if (idx < N1) {
        int frag = idx >> 9;           // (tap*5 + kc)*4 + nt
        int r    = idx & 511;
        int lane = r >> 3, j = r & 7;
        int nt = frag & 3;
        int tk = frag >> 2;            // tap*5 + kc
        int tap = tk / 5, kc = tk % 5;
        int o  = nt * 16 + (lane & 15);
        int cp = kc * 32 + (lane >> 4) * 8 + j;
        unsigned short val = 0;
        if (cp < 130) val = f2bf(ldin(w1, (o * 130 + cp) * 27 + tap, f));
        Wf1[idx] = val;
    } else if (idx < N1 + N2) {
        int i2 = idx - N1;
        int frag = i2 >> 9;            // (tap*2 + kc)*4 + nt
        int r    = i2 & 511;
        int lane = r >> 3, j = r & 7;
        int nt = frag & 3;
        int tk = frag >> 2;
        int tap = tk >> 1, kc = tk & 1;
        int o = nt * 16 + (lane & 15);
        int c = kc * 32 + (lane >> 4) * 8 + j;
        Wf2[i2] = f2bf(ldin(w2, (o * 64 + c) * 27 + tap, f));
    } else if (idx < N1 + N2 + 256) {
        int j = idx - N1 - N2;
        const void* bp = (j < 64) ? bsv : (j < 128) ? btv : (j < 192) ? b1v : b2v;
        fbias[j] = ldin(bp, j & 63, f);
    }
}

// ---------------------------------------------------------------------------
// Projection (1x1x1 conv 32->64) + L2 normalize over channels.
// ---------------------------------------------------------------------------
__global__ __launch_bounds__(256) void proj_kernel(
        const void* __restrict__ Xsrc, const void* __restrict__ Xtgt,
        const void* __restrict__ Wsrc, const void* __restrict__ Wtgt,
        const float* __restrict__ fbias, const int* __restrict__ flag,
        unsigned short* __restrict__ SP, unsigned short* __restrict__ TP) {
    const int f = *flag;
    const void* Xin = blockIdx.y ? Xtgt : Xsrc;
    const void* W   = blockIdx.y ? Wtgt : Wsrc;
    const float* Bb = fbias + (blockIdx.y ? 64 : 0);
    unsigned short* Outp = blockIdx.y ? TP : SP;

    __shared__ float ws[2048];   // [ci][o]
    const int t = threadIdx.x;
    for (int i = t; i < 2048; i += 256) {
        int ci = i >> 6, o = i & 63;
        ws[i] = ldin(W, o * 32 + ci, f);
    }
    __syncthreads();

    const size_t v = (size_t)blockIdx.x * 256 + t;
    float acc[64];
#pragma unroll
    for (int o = 0; o < 64; ++o) acc[o] = Bb[o];
    if (f) {
        const float* Xf = (const float*)Xin;
        for (int ci = 0; ci < 32; ++ci) {
            float x = Xf[(size_t)ci * NVOX + v];
            const float4* wr = (const float4*)(ws + ci * 64);
#pragma unroll
            for (int o4 = 0; o4 < 16; ++o4) {
                float4 w4 = wr[o4];
                acc[o4 * 4 + 0] = fmaf(w4.x, x, acc[o4 * 4 + 0]);
                acc[o4 * 4 + 1] = fmaf(w4.y, x, acc[o4 * 4 + 1]);
                acc[o4 * 4 + 2] = fmaf(w4.z, x, acc[o4 * 4 + 2]);
                acc[o4 * 4 + 3] = fmaf(w4.w, x, acc[o4 * 4 + 3]);
            }
        }
    } else {
        const unsigned short* Xb = (const unsigned short*)Xin;
        for (int ci = 0; ci < 32; ++ci) {
            float x = bf2f(Xb[(size_t)ci * NVOX + v]);
            const float4* wr = (const float4*)(ws + ci * 64);
#pragma unroll
            for (int o4 = 0; o4 < 16; ++o4) {
                float4 w4 = wr[o4];
                acc[o4 * 4 + 0] = fmaf(w4.x, x, acc[o4 * 4 + 0]);
                acc[o4 * 4 + 1] = fmaf(w4.y, x, acc[o4 * 4 + 1]);
                acc[o4 * 4 + 2] = fmaf(w4.z, x, acc[o4 * 4 + 2]);
                acc[o4 * 4 + 3] = fmaf(w4.w, x, acc[o4 * 4 + 3]);
            }
        }
    }
    float s = 0.f;
#pragma unroll
    for (int o = 0; o < 64; ++o) s = fmaf(acc[o], acc[o], s);
    float scale = 1.f / fmaxf(sqrtf(s), 1e-12f);

    unsigned int pk[32];
#pragma unroll
    for (int o = 0; o < 32; ++o)
        pk[o] = (unsigned int)f2bf(acc[2 * o] * scale) |
                ((unsigned int)f2bf(acc[2 * o + 1] * scale) << 16);
    uint4* outp = (uint4*)(Outp + v * 64);
#pragma unroll
    for (int j = 0; j < 8; ++j)
        outp[j] = make_uint4(pk[4 * j], pk[4 * j + 1], pk[4 * j + 2], pk[4 * j + 3]);
}

// ---------------------------------------------------------------------------
// Correlation (125 offsets, replicate pad) + online softmax/top-2 +
// enc_in assembly [v][160] bf16 + 6 fp32 output planes.
// ---------------------------------------------------------------------------
__global__ __launch_bounds__(256) void corr_kernel(
        const unsigned short* __restrict__ SP, const unsigned short* __restrict__ TP,
        unsigned short* __restrict__ X1, float* __restrict__ Out) {
    __shared__ unsigned short stage[128 * 168];
    const int t = threadIdx.x;
    const int vi = t >> 1, h = t & 1;
    const int vx = vi & 15, vy = (vi >> 4) & 3, vz = vi >> 6;
    const int X = blockIdx.x * 16 + vx, Y = blockIdx.y * 4 + vy, Z = blockIdx.z * 2 + vz;
    const size_t v = ((size_t)Z * 64 + Y) * 64 + X;

    for (int i = t; i < 128 * 30; i += 256)
        stage[(i / 30) * 168 + 130 + (i % 30)] = 0;

    float spv[32];
    {
        const uint4* p = (const uint4*)(SP + v * 64 + h * 32);
#pragma unroll
        for (int j = 0; j < 4; ++j) {
            uint4 u = p[j];
            spv[j * 8 + 0] = bflo(u.x); spv[j * 8 + 1] = bfhi(u.x);
            spv[j * 8 + 2] = bflo(u.y); spv[j * 8 + 3] = bfhi(u.y);
            spv[j * 8 + 4] = bflo(u.z); spv[j * 8 + 5] = bfhi(u.z);
            spv[j * 8 + 6] = bflo(u.w); spv[j * 8 + 7] = bfhi(u.w);
        }
    }

    float m = -1e30f, s2 = -1e30f, Zs = 0.f, S1 = 0.f, Ox = 0.f, Oy = 0.f, Oz = 0.f;
    int k = 0;
    for (int dz = -2; dz <= 2; ++dz) {
        int zc = min(max(Z + dz, 0), 63);
        for (int dy = -2; dy <= 2; ++dy) {
            int yc = min(max(Y + dy, 0), 63);
            const size_t rowb = ((size_t)zc * 64 + yc) * 64;
            for (int dx = -2; dx <= 2; ++dx, ++k) {
                int xc = min(max(X + dx, 0), 63);
                const uint4* q = (const uint4*)(TP + (rowb + xc) * 64 + h * 32);
                float d = 0.f;
#pragma unroll
                for (int j = 0; j < 4; ++j) {
                    uint4 u = q[j];
                    d = fmaf(bflo(u.x), spv[j * 8 + 0], d); d = fmaf(bfhi(u.x), spv[j * 8 + 1], d);
                    d = fmaf(bflo(u.y), spv[j * 8 + 2], d); d = fmaf(bfhi(u.y), spv[j * 8 + 3], d);
                    d = fmaf(bflo(u.z), spv[j * 8 + 4], d); d = fmaf(bfhi(u.z), spv[j * 8 + 5], d);
                    d = fmaf(bflo(u.w), spv[j * 8 + 6], d); d = fmaf(bfhi(u.w), spv[j * 8 + 7], d);
                }
                d += __shfl_xor(d, 1);
                if (h == 0) stage[vi * 168 + k] = f2bf(d);
                float fx = (float)dx, fy = (float)dy, fz = (float)dz;
                if (d > m) {
                    float sc = __expf(m - d);
                    Zs = fmaf(Zs, sc, 1.f); S1 = fmaf(S1, sc, d);
                    Ox = fmaf(Ox, sc, fx); Oy = fmaf(Oy, sc, fy); Oz = fmaf(Oz, sc, fz);
                    s2 = m; m = d;
                } else {
                    float e = __expf(d - m);
                    Zs += e; S1 = fmaf(e, d, S1);
                    Ox = fmaf(e, fx, Ox); Oy = fmaf(e, fy, Oy); Oz = fmaf(e, fz, Oz);
                    s2 = fmaxf(s2, d);
                }
            }
        }
    }

    if (h == 0) {
        float inv  = 1.f / fmaxf(Zs, 1e-8f);
        float eoz = Oz * inv, eoy = Oy * inv, eox = Ox * inv;
        float conf = fminf(inv, 1.f);
        float marg = fmaxf(conf - __expf(s2 - m) * inv, 0.f);
        float ent  = m + __logf(fmaxf(Zs, 1e-8f)) - S1 * inv;
        stage[vi * 168 + 125] = f2bf(eoz);
        stage[vi * 168 + 126] = f2bf(eoy);
        stage[vi * 168 + 127] = f2bf(eox);
        stage[vi * 168 + 128] = f2bf(conf);
        stage[vi * 168 + 129] = f2bf(ent);
        Out[v]                    = eoz;
        Out[(size_t)NVOX + v]     = eoy;
        Out[(size_t)2 * NVOX + v] = eox;
        Out[(size_t)3 * NVOX + v] = conf;
        Out[(size_t)4 * NVOX + v] = marg;
        Out[(size_t)5 * NVOX + v] = ent;
    }
    __syncthreads();

    const int bx = blockIdx.x * 16, by = blockIdx.y * 4, bz = blockIdx.z * 2;
    for (int idx = t; idx < 128 * 20; idx += 256) {
        int r = idx / 20, cc = idx % 20;
        int rx = r & 15, ry = (r >> 4) & 3, rz = r >> 6;
        size_t gv = ((size_t)(bz + rz) * 64 + (by + ry)) * 64 + (bx + rx);
        *(uint4*)(X1 + gv * 160 + (size_t)cc * 8) = *(const uint4*)(&stage[r * 168 + cc * 8]);
    }
}

// ---------------------------------------------------------------------------
// 3x3x3 conv, implicit GEMM via mfma_f32_16x16x32_bf16, zero padding.
// Block = one (z,y) x-row: 64 voxels x 64 out-ch.
// Weights come pre-packed in fragment order: Wf[tap][kc][nt][lane][8] —
// each B-fragment load is one coalesced 1 KB wave transaction, batched
// KC*4 at a time so latency is paid once per dx, not per MFMA.
// ---------------------------------------------------------------------------
template <int CPAD, int LSTRIDE, int KC>
__global__ __launch_bounds__(256) void conv3_kernel(
        const unsigned short* __restrict__ Xin, const unsigned short* __restrict__ Wf,
        const float* __restrict__ Bias, unsigned short* __restrict__ Out) {
    __shared__ unsigned short row[66 * LSTRIDE];
    // XCD-aware swizzle: XCD k gets z-slab [8k, 8k+8) for L2 halo locality.
    const int lin = blockIdx.x;
    const int z = (lin & 7) * 8 + ((lin >> 3) >> 6);
    const int y = (lin >> 3) & 63;
    const int t = threadIdx.x;
    const int wv = t >> 6, lane = t & 63;
    const int quad = lane >> 4, l16 = lane & 15;
    f32x4 acc[4] = {{0.f,0.f,0.f,0.f},{0.f,0.f,0.f,0.f},{0.f,0.f,0.f,0.f},{0.f,0.f,0.f,0.f}};
    const int CH16 = CPAD / 8;

    for (int dz = -1; dz <= 1; ++dz) {
        const int zz = z + dz;
        if (zz < 0 || zz > 63) continue;
        for (int dy = -1; dy <= 1; ++dy) {
            const int yy = y + dy;
            if (yy < 0 || yy > 63) continue;
            __syncthreads();
            for (int idx = t; idx < 66 * CH16; idx += 256) {
                int xi = idx / CH16, ci = idx % CH16;
                uint4 val = make_uint4(0u, 0u, 0u, 0u);
                int gx = xi - 1;
                if (gx >= 0 && gx < 64)
                    val = *(const uint4*)(Xin + (((size_t)zz * 64 + yy) * 64 + gx) * CPAD + ci * 8);
                *(uint4*)(&row[xi * LSTRIDE + ci * 8]) = val;
            }
            __syncthreads();
#pragma unroll
            for (int dx = -1; dx <= 1; ++dx) {
                const int tap = (dz + 1) * 9 + (dy + 1) * 3 + (dx + 1);
                const unsigned short* wtap = Wf + ((size_t)tap * KC * 4) * 512 + lane * 8;
                // batch-load all B fragments for this tap (independent loads)
                bf16x8 bf[KC][4];
#pragma unroll
                for (int kc = 0; kc < KC; ++kc)
#pragma unroll
                    for (int nt = 0; nt < 4; ++nt)
                        bf[kc][nt] = *(const bf16x8*)(wtap + (size_t)(kc * 4 + nt) * 512);
                // batch-load all A fragments for this dx from LDS
                bf16x8 af[KC];
#pragma unroll
                for (int kc = 0; kc < KC; ++kc)
                    af[kc] = *(const bf16x8*)(&row[(wv * 16 + l16 + dx + 1) * LSTRIDE + kc * 32 + quad * 8]);
#pragma unroll
                for (int kc = 0; kc < KC; ++kc)
#pragma unroll
                    for (int nt = 0; nt < 4; ++nt)
                        acc[nt] = __builtin_amdgcn_mfma_f32_16x16x32_bf16(af[kc], bf[kc][nt], acc[nt], 0, 0, 0);
            }
        }
    }

    const size_t vbase = ((size_t)z * 64 + y) * 64 + wv * 16;
#pragma unroll
    for (int nt = 0; nt < 4; ++nt) {
        const int oc = nt * 16 + l16;
        const float bv = Bias[oc];
#pragma unroll
        for (int r = 0; r < 4; ++r) {
            Out[(vbase + quad * 4 + r) * 64 + oc] = f2bf(acc[nt][r] + bv);
        }
    }
}

// ---------------------------------------------------------------------------
// Per-channel sum / sumsq over all voxels (InstanceNorm stats).
// ---------------------------------------------------------------------------
__global__ __launch_bounds__(256) void stats_kernel(
        const unsigned short* __restrict__ H, float* __restrict__ stats) {
    const int t = threadIdx.x;
    const int c = t & 63, g = t >> 6;
    float s = 0.f, q = 0.f;
    for (int v = blockIdx.x * 4 + g; v < NVOX; v += gridDim.x * 4) {
        float x = bf2f(H[(size_t)v * 64 + c]);
        s += x; q = fmaf(x, x, q);
    }
    __shared__ float ls[256], lq[256];
    ls[t] = s; lq[t] = q;
    __syncthreads();
    if (t < 64) {
        s = ls[t] + ls[t + 64] + ls[t + 128] + ls[t + 192];
        q = lq[t] + lq[t + 64] + lq[t + 128] + lq[t + 192];
        atomicAdd(&stats[c], s);
        atomicAdd(&stats[64 + c], q);
    }
}

__global__ void finalize_kernel(const float* __restrict__ stats, float* __restrict__ musr) {
    int c = threadIdx.x;
    if (c < 64) {
        float mu  = stats[c] * (1.0f / 262144.0f);
        float var = stats[64 + c] * (1.0f / 262144.0f) - mu * mu;
        musr[c] = mu;
        musr[64 + c] = rsqrtf(var + 1e-5f);
    }
}

// ---------------------------------------------------------------------------
// Elementwise InstanceNorm + exact GELU, [v][64] -> [v][64] bf16
// ---------------------------------------------------------------------------
__global__ __launch_bounds__(256) void norm_gelu_kernel(
        const unsigned short* __restrict__ H, const float* __restrict__ musr,
        unsigned short* __restrict__ G) {
    const size_t base = ((size_t)blockIdx.x * 256 + threadIdx.x) * 8;
    uint4 u = *(const uint4*)(H + base);
    const int c0 = (int)(base & 63);
    const unsigned int uu[4] = {u.x, u.y, u.z, u.w};
    unsigned int w[4];
#pragma unroll
    for (int p = 0; p < 4; ++p) {
        int c = c0 + p * 2;
        float x0 = (bflo(uu[p]) - musr[c]) * musr[64 + c];
        float x1 = (bfhi(uu[p]) - musr[c + 1]) * musr[64 + c + 1];
        float g0 = 0.5f * x0 * (1.f + erff(x0 * 0.70710678118f));
        float g1 = 0.5f * x1 * (1.f + erff(x1 * 0.70710678118f));
        w[p] = (unsigned int)f2bf(g0) | ((unsigned int)f2bf(g1) << 16);
    }
    *(uint4*)(G + base) = make_uint4(w[0], w[1], w[2], w[3]);
}

// ---------------------------------------------------------------------------
// Final: InstanceNorm + exact GELU on h2, write fp32 channel planes [64][v].
// ---------------------------------------------------------------------------
__global__ __launch_bounds__(256) void out_final_kernel(
        const unsigned short* __restrict__ H2, const float* __restrict__ musr,
        float* __restrict__ OutEnc) {
    __shared__ float tile[64 * 260];
    const int t = threadIdx.x;
    const size_t v0 = (size_t)blockIdx.x * 256;
#pragma unroll
    for (int i = 0; i < 8; ++i) {
        int chunk = t + i * 256;                  // 0..2047
        uint4 u = *(const uint4*)(H2 + v0 * 64 + (size_t)chunk * 8);
        int vox = chunk >> 3;
        int c0 = (chunk & 7) * 8;
        const unsigned int uu[4] = {u.x, u.y, u.z, u.w};
#pragma unroll
        for (int p = 0; p < 4; ++p) {
            int c = c0 + p * 2;
            float x0 = (bflo(uu[p]) - musr[c]) * musr[64 + c];
            float x1 = (bfhi(uu[p]) - musr[c + 1]) * musr[64 + c + 1];
            tile[c * 260 + vox]       = 0.5f * x0 * (1.f + erff(x0 * 0.70710678118f));
            tile[(c + 1) * 260 + vox] = 0.5f * x1 * (1.f + erff(x1 * 0.70710678118f));
        }
    }
    __syncthreads();
    const int c = t >> 2, sub = t & 3;
#pragma unroll
    for (int iter = 0; iter < 16; ++iter) {
        int fq = iter * 4 + sub;                  // float4 index 0..63
        float4 val = *(const float4*)(&tile[c * 260 + fq * 4]);
        *(float4*)(OutEnc + (size_t)c * NVOX + v0 + fq * 4) = val;
    }
}

// ---------------------------------------------------------------------------
extern "C" void kernel_launch(void* const* d_in, const int* in_sizes, int n_in,
                              void* d_out, int out_size, void* d_ws, size_t ws_size,
                              hipStream_t stream) {
    const void* src  = d_in[0];
    const void* tgt  = d_in[1];
    const void* wsrc = d_in[2];
    const void* bsrc = d_in[3];
    const void* wtgt = d_in[4];
    const void* btgt = d_in[5];
    const void* w1   = d_in[6];
    const void* b1   = d_in[7];
    const void* w2   = d_in[8];
    const void* b2   = d_in[9];
    float* out = (float*)d_out;   // fp32 outputs, 70*262144 elements

    char* ws = (char*)d_ws;
    unsigned short* TPb = (unsigned short*)(ws);                  // 33,554,432 B
    unsigned short* SPb = (unsigned short*)(ws + 33554432);       // 33,554,432 B
    unsigned short* X1  = (unsigned short*)(ws + 67108864);       // 83,886,080 B
    unsigned short* Wf1 = (unsigned short*)(ws + 150994944);      //    552,960 B
    unsigned short* Wf2 = (unsigned short*)(ws + 151547904);      //    221,184 B
    int*   flag   = (int*)  (ws + 151769088);
    float* fbias  = (float*)(ws + 151769152);                     // 256 f32
    float* stats1 = (float*)(ws + 151770176);                     // 128 f32
    float* musr1  = (float*)(ws + 151770688);
    float* stats2 = (float*)(ws + 151771200);
    float* musr2  = (float*)(ws + 151771712);
    unsigned short* H1 = SPb;
    unsigned short* G1 = TPb;
    unsigned short* H2 = X1;

    (void)hipMemsetAsync(stats1, 0, 2048, stream);
    sniff_kernel<<<1, 256, 0, stream>>>((const unsigned short*)src, flag);
    prep_kernel<<<1513, 256, 0, stream>>>(w1, w2, bsrc, btgt, b1, b2, flag, Wf1, Wf2, fbias);
    proj_kernel<<<dim3(1024, 2), 256, 0, stream>>>(src, tgt, wsrc, wtgt, fbias, flag, SPb, TPb);
    corr_kernel<<<dim3(4, 16, 32), 256, 0, stream>>>(SPb, TPb, X1, out);
    conv3_kernel<160, 168, 5><<<4096, 256, 0, stream>>>(X1, Wf1, fbias + 128, H1);
    stats_kernel<<<256, 256, 0, stream>>>(H1, stats1);
    finalize_kernel<<<1, 64, 0, stream>>>(stats1, musr1);
    norm_gelu_kernel<<<8192, 256, 0, stream>>>(H1, musr1, G1);
    conv3_kernel<64, 72, 2><<<4096, 256, 0, stream>>>(G1, Wf2, fbias + 192, H2);
    stats_kernel<<<256, 256, 0, stream>>>(H2, stats2);
    finalize_kernel<<<1, 64, 0, stream>>>(stats2, musr2);
    out_final_kernel<<<1024, 256, 0, stream>>>(H2, musr2, out + 6 * (size_t)NVOX);
}

// Round 5
// 918.563 us; speedup vs baseline: 1.7297x; 1.1215x over previous
//
#include <hip/hip_runtime.h>

#define DEV __device__ __forceinline__

typedef short bf16x8 __attribute__((ext_vector_type(8)));
typedef float f32x4 __attribute__((ext_vector_type(4)));

static const int NVOX = 262144; // 64^3

DEV float bflo(unsigned int u) { return __uint_as_float(u << 16); }
DEV float bfhi(unsigned int u) { return __uint_as_float(u & 0xffff0000u); }
DEV float bf2f(unsigned short s) { return __uint_as_float(((unsigned int)s) << 16); }
DEV unsigned short f2bf(float f) {
    unsigned int x = __float_as_uint(f);
    x += 0x7fffu + ((x >> 16) & 1u);   // RNE
    return (unsigned short)(x >> 16);
}
// dual-dtype raw-input load: f==1 -> fp32, f==0 -> bf16
DEV float ldin(const void* p, int i, int f) {
    return f ? ((const float*)p)[i] : bf2f(((const unsigned short*)p)[i]);
}

// ---------------------------------------------------------------------------
// Dtype sniffer (insurance; R3 confirmed fp32 inputs).
// ---------------------------------------------------------------------------
__global__ void sniff_kernel(const unsigned short* __restrict__ src, int* __restrict__ flag) {
    __shared__ int cnt[256];
    int t = threadIdx.x;
    int c = 0;
    for (int i = t; i < 4096; i += 256) {
        unsigned int u = (unsigned int)src[i] & 0x7fffu;
        c += (u >= 0x4900u) ? 1 : 0;
    }
    cnt[t] = c;
    __syncthreads();
    for (int s = 128; s > 0; s >>= 1) {
        if (t < s) cnt[t] += cnt[t + s];
        __syncthreads();
    }
    if (t == 0) *flag = (cnt[0] > 8) ? 1 : 0;
}

// ---------------------------------------------------------------------------
// Weight prep into MFMA B-fragment order:
//   Wf[tap][kc][nt][lane][j]  (j=0..7, lane=0..63), 512 shorts per fragment.
//   Fragment element (lane,j) = W[o = nt*16 + (lane&15)][cp = kc*32 + (lane>>4)*8 + j]
// ---------------------------------------------------------------------------
__global__ void prep_kernel(const void* __restrict__ w1, const void* __restrict__ w2,
                            const void* __restrict__ bsv, const void* __restrict__ btv,
                            const void* __restrict__ b1v, const void* __restrict__ b2v,
                            const int* __restrict__ flag,
                            unsigned short* __restrict__ Wf1,
                            unsigned short* __restrict__ Wf2,
                            float* __restrict__ fbias) {
    const int f = *flag;
    int idx = blockIdx.x * 256 + threadIdx.x;
    const int N1 = 27 * 5 * 4 * 512;   // 276480
    const int N2 = 27 * 2 * 4 * 512;   // 110592
    if (idx < N1) {
        int frag = idx >> 9;           // (tap*5 + kc)*4 + nt
        int r    = idx & 511;
        int lane = r >> 3, j = r & 7;
        int nt = frag & 3;
        int tk = frag >> 2;            // tap*5 + kc
        int tap = tk / 5, kc = tk % 5;
        int o  = nt * 16 + (lane & 15);
        int cp = kc * 32 + (lane >> 4) * 8 + j;
        unsigned short val = 0;
        if (cp < 130) val = f2bf(ldin(w1, (o * 130 + cp) * 27 + tap, f));
        Wf1[idx] = val;
    } else if (idx < N1 + N2) {
        int i2 = idx - N1;
        int frag = i2 >> 9;            // (tap*2 + kc)*4 + nt
        int r    = i2 & 511;
        int lane = r >> 3, j = r & 7;
        int nt = frag & 3;
        int tk = frag >> 2;
        int tap = tk >> 1, kc = tk & 1;
        int o = nt * 16 + (lane & 15);
        int c = kc * 32 + (lane >> 4) * 8 + j;
        Wf2[i2] = f2bf(ldin(w2, (o * 64 + c) * 27 + tap, f));
    } else if (idx < N1 + N2 + 256) {
        int j = idx - N1 - N2;
        const void* bp = (j < 64) ? bsv : (j < 128) ? btv : (j < 192) ? b1v : b2v;
        fbias[j] = ldin(bp, j & 63, f);
    }
}

// ---------------------------------------------------------------------------
// Projection (1x1x1 conv 32->64) + L2 normalize over channels.
// ---------------------------------------------------------------------------
__global__ __launch_bounds__(256) void proj_kernel(
        const void* __restrict__ Xsrc, const void* __restrict__ Xtgt,
        const void* __restrict__ Wsrc, const void* __restrict__ Wtgt,
        const float* __restrict__ fbias, const int* __restrict__ flag,
        unsigned short* __restrict__ SP, unsigned short* __restrict__ TP) {
    const int f = *flag;
    const void* Xin = blockIdx.y ? Xtgt : Xsrc;
    const void* W   = blockIdx.y ? Wtgt : Wsrc;
    const float* Bb = fbias + (blockIdx.y ? 64 : 0);
    unsigned short* Outp = blockIdx.y ? TP : SP;

    __shared__ float ws[2048];   // [ci][o]
    const int t = threadIdx.x;
    for (int i = t; i < 2048; i += 256) {
        int ci = i >> 6, o = i & 63;
        ws[i] = ldin(W, o * 32 + ci, f);
    }
    __syncthreads();

    const size_t v = (size_t)blockIdx.x * 256 + t;
    float acc[64];
#pragma unroll
    for (int o = 0; o < 64; ++o) acc[o] = Bb[o];
    if (f) {
        const float* Xf = (const float*)Xin;
        for (int ci = 0; ci < 32; ++ci) {
            float x = Xf[(size_t)ci * NVOX + v];
            const float4* wr = (const float4*)(ws + ci * 64);
#pragma unroll
            for (int o4 = 0; o4 < 16; ++o4) {
                float4 w4 = wr[o4];
                acc[o4 * 4 + 0] = fmaf(w4.x, x, acc[o4 * 4 + 0]);
                acc[o4 * 4 + 1] = fmaf(w4.y, x, acc[o4 * 4 + 1]);
                acc[o4 * 4 + 2] = fmaf(w4.z, x, acc[o4 * 4 + 2]);
                acc[o4 * 4 + 3] = fmaf(w4.w, x, acc[o4 * 4 + 3]);
            }
        }
    } else {
        const unsigned short* Xb = (const unsigned short*)Xin;
        for (int ci = 0; ci < 32; ++ci) {
            float x = bf2f(Xb[(size_t)ci * NVOX + v]);
            const float4* wr = (const float4*)(ws + ci * 64);
#pragma unroll
            for (int o4 = 0; o4 < 16; ++o4) {
                float4 w4 = wr[o4];
                acc[o4 * 4 + 0] = fmaf(w4.x, x, acc[o4 * 4 + 0]);
                acc[o4 * 4 + 1] = fmaf(w4.y, x, acc[o4 * 4 + 1]);
                acc[o4 * 4 + 2] = fmaf(w4.z, x, acc[o4 * 4 + 2]);
                acc[o4 * 4 + 3] = fmaf(w4.w, x, acc[o4 * 4 + 3]);
            }
        }
    }
    float s = 0.f;
#pragma unroll
    for (int o = 0; o < 64; ++o) s = fmaf(acc[o], acc[o], s);
    float scale = 1.f / fmaxf(sqrtf(s), 1e-12f);

    unsigned int pk[32];
#pragma unroll
    for (int o = 0; o < 32; ++o)
        pk[o] = (unsigned int)f2bf(acc[2 * o] * scale) |
                ((unsigned int)f2bf(acc[2 * o + 1] * scale) << 16);
    uint4* outp = (uint4*)(Outp + v * 64);
#pragma unroll
    for (int j = 0; j < 8; ++j)
        outp[j] = make_uint4(pk[4 * j], pk[4 * j + 1], pk[4 * j + 2], pk[4 * j + 3]);
}

// ---------------------------------------------------------------------------
// Correlation (125 offsets, replicate pad) + online softmax/top-2 +
// enc_in assembly [v][160] bf16 + 6 fp32 output planes.
// ---------------------------------------------------------------------------
__global__ __launch_bounds__(256) void corr_kernel(
        const unsigned short* __restrict__ SP, const unsigned short* __restrict__ TP,
        unsigned short* __restrict__ X1, float* __restrict__ Out) {
    __shared__ unsigned short stage[128 * 168];
    const int t = threadIdx.x;
    const int vi = t >> 1, h = t & 1;
    const int vx = vi & 15, vy = (vi >> 4) & 3, vz = vi >> 6;
    const int X = blockIdx.x * 16 + vx, Y = blockIdx.y * 4 + vy, Z = blockIdx.z * 2 + vz;
    const size_t v = ((size_t)Z * 64 + Y) * 64 + X;

    for (int i = t; i < 128 * 30; i += 256)
        stage[(i / 30) * 168 + 130 + (i % 30)] = 0;

    float spv[32];
    {
        const uint4* p = (const uint4*)(SP + v * 64 + h * 32);
#pragma unroll
        for (int j = 0; j < 4; ++j) {
            uint4 u = p[j];
            spv[j * 8 + 0] = bflo(u.x); spv[j * 8 + 1] = bfhi(u.x);
            spv[j * 8 + 2] = bflo(u.y); spv[j * 8 + 3] = bfhi(u.y);
            spv[j * 8 + 4] = bflo(u.z); spv[j * 8 + 5] = bfhi(u.z);
            spv[j * 8 + 6] = bflo(u.w); spv[j * 8 + 7] = bfhi(u.w);
        }
    }

    float m = -1e30f, s2 = -1e30f, Zs = 0.f, S1 = 0.f, Ox = 0.f, Oy = 0.f, Oz = 0.f;
    int k = 0;
    for (int dz = -2; dz <= 2; ++dz) {
        int zc = min(max(Z + dz, 0), 63);
        for (int dy = -2; dy <= 2; ++dy) {
            int yc = min(max(Y + dy, 0), 63);
            const size_t rowb = ((size_t)zc * 64 + yc) * 64;
            for (int dx = -2; dx <= 2; ++dx, ++k) {
                int xc = min(max(X + dx, 0), 63);
                const uint4* q = (const uint4*)(TP + (rowb + xc) * 64 + h * 32);
                float d = 0.f;
#pragma unroll
                for (int j = 0; j < 4; ++j) {
                    uint4 u = q[j];
                    d = fmaf(bflo(u.x), spv[j * 8 + 0], d); d = fmaf(bfhi(u.x), spv[j * 8 + 1], d);
                    d = fmaf(bflo(u.y), spv[j * 8 + 2], d); d = fmaf(bfhi(u.y), spv[j * 8 + 3], d);
                    d = fmaf(bflo(u.z), spv[j * 8 + 4], d); d = fmaf(bfhi(u.z), spv[j * 8 + 5], d);
                    d = fmaf(bflo(u.w), spv[j * 8 + 6], d); d = fmaf(bfhi(u.w), spv[j * 8 + 7], d);
                }
                d += __shfl_xor(d, 1);
                if (h == 0) stage[vi * 168 + k] = f2bf(d);
                float fx = (float)dx, fy = (float)dy, fz = (float)dz;
                if (d > m) {
                    float sc = __expf(m - d);
                    Zs = fmaf(Zs, sc, 1.f); S1 = fmaf(S1, sc, d);
                    Ox = fmaf(Ox, sc, fx); Oy = fmaf(Oy, sc, fy); Oz = fmaf(Oz, sc, fz);
                    s2 = m; m = d;
                } else {
                    float e = __expf(d - m);
                    Zs += e; S1 = fmaf(e, d, S1);
                    Ox = fmaf(e, fx, Ox); Oy = fmaf(e, fy, Oy); Oz = fmaf(e, fz, Oz);
                    s2 = fmaxf(s2, d);
                }
            }
        }
    }

    if (h == 0) {
        float inv  = 1.f / fmaxf(Zs, 1e-8f);
        float eoz = Oz * inv, eoy = Oy * inv, eox = Ox * inv;
        float conf = fminf(inv, 1.f);
        float marg = fmaxf(conf - __expf(s2 - m) * inv, 0.f);
        float ent  = m + __logf(fmaxf(Zs, 1e-8f)) - S1 * inv;
        stage[vi * 168 + 125] = f2bf(eoz);
        stage[vi * 168 + 126] = f2bf(eoy);
        stage[vi * 168 + 127] = f2bf(eox);
        stage[vi * 168 + 128] = f2bf(conf);
        stage[vi * 168 + 129] = f2bf(ent);
        Out[v]                    = eoz;
        Out[(size_t)NVOX + v]     = eoy;
        Out[(size_t)2 * NVOX + v] = eox;
        Out[(size_t)3 * NVOX + v] = conf;
        Out[(size_t)4 * NVOX + v] = marg;
        Out[(size_t)5 * NVOX + v] = ent;
    }
    __syncthreads();

    const int bx = blockIdx.x * 16, by = blockIdx.y * 4, bz = blockIdx.z * 2;
    for (int idx = t; idx < 128 * 20; idx += 256) {
        int r = idx / 20, cc = idx % 20;
        int rx = r & 15, ry = (r >> 4) & 3, rz = r >> 6;
        size_t gv = ((size_t)(bz + rz) * 64 + (by + ry)) * 64 + (bx + rx);
        *(uint4*)(X1 + gv * 160 + (size_t)cc * 8) = *(const uint4*)(&stage[r * 168 + cc * 8]);
    }
}

// ---------------------------------------------------------------------------
// 3x3x3 conv, implicit GEMM via mfma_f32_16x16x32_bf16, zero padding.
// Block = one (z,y) x-row: 64 voxels x 64 out-ch.
// Hybrid 2x2 wave tiling: wave owns 2 M-tiles x 2 N-tiles (balances B global
// traffic vs A LDS traffic). Double-buffered staging, one barrier per
// (dz,dy) iteration, next iteration's rows prefetched into registers during
// MFMA. Invalid halo rows stage zeros (zero-pad conv => harmless MFMAs) so
// all blocks run a uniform 9-iteration loop.
// ---------------------------------------------------------------------------
template <int CPAD, int LSTRIDE, int KC, int NLD>
__global__ __launch_bounds__(256) void conv3_kernel(
        const unsigned short* __restrict__ Xin, const unsigned short* __restrict__ Wf,
        const float* __restrict__ Bias, unsigned short* __restrict__ Out) {
    __shared__ unsigned short rowbuf[2][66 * LSTRIDE];
    const int lin = blockIdx.x;
    const int z = (lin & 7) * 8 + ((lin >> 3) >> 6);
    const int y = (lin >> 3) & 63;
    const int t = threadIdx.x;
    const int wv = t >> 6, lane = t & 63;
    const int quad = lane >> 4, l16 = lane & 15;
    const int mt2 = (wv & 1) * 2;    // m-tile pair base
    const int nt2 = (wv >> 1) * 2;   // n-tile pair base
    const int CH16 = CPAD / 8;

    f32x4 acc[2][2] = {{{0.f,0.f,0.f,0.f},{0.f,0.f,0.f,0.f}},
                       {{0.f,0.f,0.f,0.f},{0.f,0.f,0.f,0.f}}};

    uint4 pre[NLD];
    // prologue: loads for iteration 0 (dz=-1, dy=-1)
    {
        const int zz = z - 1, yy = y - 1;
        const bool valid = (unsigned)zz < 64u && (unsigned)yy < 64u;
        const unsigned short* base = Xin + (((size_t)(valid ? zz : 0) * 64 + (valid ? yy : 0)) * 64) * CPAD;
#pragma unroll
        for (int i = 0; i < NLD; ++i) {
            int idx = t + i * 256;
            uint4 val = make_uint4(0u, 0u, 0u, 0u);
            if (idx < 66 * CH16) {
                int xi = idx / CH16, ci = idx % CH16;
                int gx = xi - 1;
                if (valid && gx >= 0 && gx < 64) val = *(const uint4*)(base + gx * CPAD + ci * 8);
            }
            pre[i] = val;
        }
    }

    int p = 0;
    for (int it = 0; it < 9; ++it) {
        // commit prefetched rows into LDS buffer p
#pragma unroll
        for (int i = 0; i < NLD; ++i) {
            int idx = t + i * 256;
            if (idx < 66 * CH16) {
                int xi = idx / CH16, ci = idx % CH16;
                *(uint4*)(&rowbuf[p][xi * LSTRIDE + ci * 8]) = pre[i];
            }
        }
        __syncthreads();
        // issue next iteration's loads (overlaps the MFMA work below)
        if (it < 8) {
            const int itn = it + 1;
            const int zz = z + itn / 3 - 1, yy = y + itn % 3 - 1;
            const bool valid = (unsigned)zz < 64u && (unsigned)yy < 64u;
            const unsigned short* base = Xin + (((size_t)(valid ? zz : 0) * 64 + (valid ? yy : 0)) * 64) * CPAD;
#pragma unroll
            for (int i = 0; i < NLD; ++i) {
                int idx = t + i * 256;
                uint4 val = make_uint4(0u, 0u, 0u, 0u);
                if (idx < 66 * CH16) {
                    int xi = idx / CH16, ci = idx % CH16;
                    int gx = xi - 1;
                    if (valid && gx >= 0 && gx < 64) val = *(const uint4*)(base + gx * CPAD + ci * 8);
                }
                pre[i] = val;
            }
        }
        const unsigned short* rp = rowbuf[p];
#pragma unroll
        for (int dx = 0; dx < 3; ++dx) {
            const int tap = it * 3 + dx;
            const unsigned short* wt = Wf + ((size_t)tap * KC * 4) * 512 + lane * 8;
            bf16x8 bf[KC][2];
#pragma unroll
            for (int kc = 0; kc < KC; ++kc)
#pragma unroll
                for (int nl = 0; nl < 2; ++nl)
                    bf[kc][nl] = *(const bf16x8*)(wt + (size_t)(kc * 4 + nt2 + nl) * 512);
#pragma unroll
            for (int kc = 0; kc < KC; ++kc) {
#pragma unroll
                for (int ml = 0; ml < 2; ++ml) {
                    bf16x8 a = *(const bf16x8*)(&rp[((mt2 + ml) * 16 + l16 + dx) * LSTRIDE + kc * 32 + quad * 8]);
#pragma unroll
                    for (int nl = 0; nl < 2; ++nl)
                        acc[ml][nl] = __builtin_amdgcn_mfma_f32_16x16x32_bf16(a, bf[kc][nl], acc[ml][nl], 0, 0, 0);
                }
            }
        }
        p ^= 1;
    }

    const size_t vbase = ((size_t)z * 64 + y) * 64;
#pragma unroll
    for (int ml = 0; ml < 2; ++ml) {
#pragma unroll
        for (int nl = 0; nl < 2; ++nl) {
            const int oc = (nt2 + nl) * 16 + l16;
            const float bv = Bias[oc];
#pragma unroll
            for (int r = 0; r < 4; ++r)
                Out[(vbase + (mt2 + ml) * 16 + quad * 4 + r) * 64 + oc] = f2bf(acc[ml][nl][r] + bv);
        }
    }
}

// ---------------------------------------------------------------------------
// Per-channel sum / sumsq over all voxels (InstanceNorm stats).
// ---------------------------------------------------------------------------
__global__ __launch_bounds__(256) void stats_kernel(
        const unsigned short* __restrict__ H, float* __restrict__ stats) {
    const int t = threadIdx.x;
    const int c = t & 63, g = t >> 6;
    float s = 0.f, q = 0.f;
    for (int v = blockIdx.x * 4 + g; v < NVOX; v += gridDim.x * 4) {
        float x = bf2f(H[(size_t)v * 64 + c]);
        s += x; q = fmaf(x, x, q);
    }
    __shared__ float ls[256], lq[256];
    ls[t] = s; lq[t] = q;
    __syncthreads();
    if (t < 64) {
        s = ls[t] + ls[t + 64] + ls[t + 128] + ls[t + 192];
        q = lq[t] + lq[t + 64] + lq[t + 128] + lq[t + 192];
        atomicAdd(&stats[c], s);
        atomicAdd(&stats[64 + c], q);
    }
}

__global__ void finalize_kernel(const float* __restrict__ stats, float* __restrict__ musr) {
    int c = threadIdx.x;
    if (c < 64) {
        float mu  = stats[c] * (1.0f / 262144.0f);
        float var = stats[64 + c] * (1.0f / 262144.0f) - mu * mu;
        musr[c] = mu;
        musr[64 + c] = rsqrtf(var + 1e-5f);
    }
}

// ---------------------------------------------------------------------------
// Elementwise InstanceNorm + exact GELU, [v][64] -> [v][64] bf16
// ---------------------------------------------------------------------------
__global__ __launch_bounds__(256) void norm_gelu_kernel(
        const unsigned short* __restrict__ H, const float* __restrict__ musr,
        unsigned short* __restrict__ G) {
    const size_t base = ((size_t)blockIdx.x * 256 + threadIdx.x) * 8;
    uint4 u = *(const uint4*)(H + base);
    const int c0 = (int)(base & 63);
    const unsigned int uu[4] = {u.x, u.y, u.z, u.w};
    unsigned int w[4];
#pragma unroll
    for (int p = 0; p < 4; ++p) {
        int c = c0 + p * 2;
        float x0 = (bflo(uu[p]) - musr[c]) * musr[64 + c];
        float x1 = (bfhi(uu[p]) - musr[c + 1]) * musr[64 + c + 1];
        float g0 = 0.5f * x0 * (1.f + erff(x0 * 0.70710678118f));
        float g1 = 0.5f * x1 * (1.f + erff(x1 * 0.70710678118f));
        w[p] = (unsigned int)f2bf(g0) | ((unsigned int)f2bf(g1) << 16);
    }
    *(uint4*)(G + base) = make_uint4(w[0], w[1], w[2], w[3]);
}

// ---------------------------------------------------------------------------
// Final: InstanceNorm + exact GELU on h2, write fp32 channel planes [64][v].
// ---------------------------------------------------------------------------
__global__ __launch_bounds__(256) void out_final_kernel(
        const unsigned short* __restrict__ H2, const float* __restrict__ musr,
        float* __restrict__ OutEnc) {
    __shared__ float tile[64 * 260];
    const int t = threadIdx.x;
    const size_t v0 = (size_t)blockIdx.x * 256;
#pragma unroll
    for (int i = 0; i < 8; ++i) {
        int chunk = t + i * 256;                  // 0..2047
        uint4 u = *(const uint4*)(H2 + v0 * 64 + (size_t)chunk * 8);
        int vox = chunk >> 3;
        int c0 = (chunk & 7) * 8;
        const unsigned int uu[4] = {u.x, u.y, u.z, u.w};
#pragma unroll
        for (int p = 0; p < 4; ++p) {
            int c = c0 + p * 2;
            float x0 = (bflo(uu[p]) - musr[c]) * musr[64 + c];
            float x1 = (bfhi(uu[p]) - musr[c + 1]) * musr[64 + c + 1];
            tile[c * 260 + vox]       = 0.5f * x0 * (1.f + erff(x0 * 0.70710678118f));
            tile[(c + 1) * 260 + vox] = 0.5f * x1 * (1.f + erff(x1 * 0.70710678118f));
        }
    }
    __syncthreads();
    const int c = t >> 2, sub = t & 3;
#pragma unroll
    for (int iter = 0; iter < 16; ++iter) {
        int fq = iter * 4 + sub;                  // float4 index 0..63
        float4 val = *(const float4*)(&tile[c * 260 + fq * 4]);
        *(float4*)(OutEnc + (size_t)c * NVOX + v0 + fq * 4) = val;
    }
}

// ---------------------------------------------------------------------------
extern "C" void kernel_launch(void* const* d_in, const int* in_sizes, int n_in,
                              void* d_out, int out_size, void* d_ws, size_t ws_size,
                              hipStream_t stream) {
    const void* src  = d_in[0];
    const void* tgt  = d_in[1];
    const void* wsrc = d_in[2];
    const void* bsrc = d_in[3];
    const void* wtgt = d_in[4];
    const void* btgt = d_in[5];
    const void* w1   = d_in[6];
    const void* b1   = d_in[7];
    const void* w2   = d_in[8];
    const void* b2   = d_in[9];
    float* out = (float*)d_out;   // fp32 outputs, 70*262144 elements

    char* ws = (char*)d_ws;
    unsigned short* TPb = (unsigned short*)(ws);                  // 33,554,432 B
    unsigned short* SPb = (unsigned short*)(ws + 33554432);       // 33,554,432 B
    unsigned short* X1  = (unsigned short*)(ws + 67108864);       // 83,886,080 B
    unsigned short* Wf1 = (unsigned short*)(ws + 150994944);      //    552,960 B
    unsigned short* Wf2 = (unsigned short*)(ws + 151547904);      //    221,184 B
    int*   flag   = (int*)  (ws + 151769088);
    float* fbias  = (float*)(ws + 151769152);                     // 256 f32
    float* stats1 = (float*)(ws + 151770176);                     // 128 f32
    float* musr1  = (float*)(ws + 151770688);
    float* stats2 = (float*)(ws + 151771200);
    float* musr2  = (float*)(ws + 151771712);
    unsigned short* H1 = SPb;
    unsigned short* G1 = TPb;
    unsigned short* H2 = X1;

    (void)hipMemsetAsync(stats1, 0, 2048, stream);
    sniff_kernel<<<1, 256, 0, stream>>>((const unsigned short*)src, flag);
    prep_kernel<<<1513, 256, 0, stream>>>(w1, w2, bsrc, btgt, b1, b2, flag, Wf1, Wf2, fbias);
    proj_kernel<<<dim3(1024, 2), 256, 0, stream>>>(src, tgt, wsrc, wtgt, fbias, flag, SPb, TPb);
    corr_kernel<<<dim3(4, 16, 32), 256, 0, stream>>>(SPb, TPb, X1, out);
    conv3_kernel<160, 168, 5, 6><<<4096, 256, 0, stream>>>(X1, Wf1, fbias + 128, H1);
    stats_kernel<<<256, 256, 0, stream>>>(H1, stats1);
    finalize_kernel<<<1, 64, 0, stream>>>(stats1, musr1);
    norm_gelu_kernel<<<8192, 256, 0, stream>>>(H1, musr1, G1);
    conv3_kernel<64, 72, 2, 3><<<4096, 256, 0, stream>>>(G1, Wf2, fbias + 192, H2);
    stats_kernel<<<256, 256, 0, stream>>>(H2, stats2);
    finalize_kernel<<<1, 64, 0, stream>>>(stats2, musr2);
    out_final_kernel<<<1024, 256, 0, stream>>>(H2, musr2, out + 6 * (size_t)NVOX);
}